// Round 8
// baseline (1513.170 us; speedup 1.0000x reference)
//
#include <hip/hip_runtime.h>

// CostVolume2D: N=8, C=128, H=96, W=224, D=4 -> 81 channels.
// out[n, dy*9+dx, h, w] = mean_c f1[n,c,h,w] * f2[n,c,h+dy-4,w+dx-4] (0 if OOB)
//
// Round 12 = round 11 with __launch_bounds__ REMOVED (single variable).
// R11 post-mortem: (64,2) produced VGPR=64 + 582MB scratch writes -- worse
// cap than (64,3)'s 84. Cross-round data ((192,6)->40, (64,3)->84, (64,2)->64)
// falsifies any monotone cap law: with a waves-per-eu floor attribute set,
// the backend chases an occupancy target and spills to reach it. The only
// no-spill configs were ones whose natural pressure already fit. So: no
// launch_bounds -> allocator takes what the body needs (~100-115 VGPR),
// hardware then gives 512/VGPR ~= 4 waves/SIMD = ~16 independent waves/CU.
// R11 confirmed the structure itself: barrier-free single-buffer LDS is
// correct, and 1-wave blocks reached 40% occupancy even while spilling.
//
// Structure (unchanged from R11):
//  - block = 1 wave; grid 672 tiles x 9 dy = 6048 blocks (23.6 waves/CU
//    offered); all waves mutually independent, zero barriers.
//  - LDS: single 1792B buffer (16 rows x 28 stride), wave-private;
//    write(c+1) -> FMA(c) -> read frags(c+1) ordered by same-wave ds pipe.
//  - staging: 96 contiguous float4 granules (16 rows x 6), <=2 slots/thread;
//    2-deep register prefetch for f2-staging and f1.
//  - per thread: 4 w-px x 9 dx = 36 fp32 accumulators, 36 FMA/channel.

constexpr int Cn = 128;
constexpr int Hh = 96;
constexpr int Ww = 224;
constexpr int HW = Hh * Ww;       // 21504
constexpr int TILE_H = 16;
constexpr int TILE_W = 16;
constexpr int NROW = 16;          // staged rows: single dy needs exactly 16
constexpr int F2S  = 28;          // row stride floats: gy,gy+8 alias = 2-way (free)
constexpr int CT   = NROW * F2S;  // 448 floats = 1792 B
constexpr int NG   = 6;           // float4 granules per row (24 staged cols)
constexpr int SLOTS = NROW * NG;  // 96 slots; thread t covers t and t+64

__global__ void costvol_kernel(const float* __restrict__ f1g,
                               const float* __restrict__ f2g,
                               float* __restrict__ outg) {
    __shared__ float lds[CT];          // single buffer, wave-private

    const int b    = blockIdx.x;
    const int xcd  = b & 7;            // consecutive block IDs round-robin XCDs
    const int j    = b >> 3;           // 0..755
    const int dy   = j % 9;
    const int tp   = j / 9;            // 0..83
    const int tile = tp * 8 + xcd;     // a tile's 9 dy-waves -> same XCD
    const int wt   = tile % 14;
    const int ht   = (tile / 14) % 6;
    const int n    = tile / 84;

    const int h0 = ht * TILE_H;
    const int w0 = wt * TILE_W;

    const int lane = threadIdx.x;
    const int gx   = lane & 3;         // 4 w px: w = w0 + 4*gx + (0..3)
    const int gy   = lane >> 2;        // h row: h = h0 + gy
    const int hA   = h0 + gy;
    const int wA   = w0 + 4 * gx;

    const size_t nbase = (size_t)n * Cn * HW;
    const float* f1n = f1g + nbase;
    const float* f2n = f2g + nbase;

    // ---- staging geometry: slot s -> row s/6, granule s%6 ----
    // f2 row y = h0 + dy - 4 + r ; col x = w0 - 4 + 4*g (granule fully in/out)
    bool sAct[2], sVal[2];
    const float* f2sp[2];
    int sLds[2];
#pragma unroll
    for (int k = 0; k < 2; ++k) {
        const int s = lane + 64 * k;
        sAct[k] = (s < SLOTS);
        const int r = s / NG;
        const int g = s - r * NG;
        const int y = h0 + dy - 4 + r;
        const int x = w0 - 4 + 4 * g;
        sVal[k] = sAct[k] && (y >= 0) && (y < Hh) && (x >= 0) && (x < Ww);
        f2sp[k] = f2n + (sVal[k] ? (y * Ww + x) : 0);
        sLds[k] = r * F2S + 4 * g;
    }

    const float* f1b = f1n + hA * Ww + wA;
    const float* ldr = &lds[gy * F2S + 4 * gx];   // 12-float window base

    float4 acc[9];
#pragma unroll
    for (int dx = 0; dx < 9; ++dx)
        acc[dx] = make_float4(0.f, 0.f, 0.f, 0.f);

    const float4 z4 = make_float4(0.f, 0.f, 0.f, 0.f);

    // ---- prologue: stage ch0; prime 2-deep pipeline ----
    float4 stA[2], stB[2];
#pragma unroll
    for (int k = 0; k < 2; ++k) {
        const float4 v = sVal[k] ? *(const float4*)(f2sp[k]) : z4;
        if (sAct[k]) *(float4*)(&lds[sLds[k]]) = v;
    }
#pragma unroll
    for (int k = 0; k < 2; ++k)
        stA[k] = sVal[k] ? *(const float4*)(f2sp[k] + HW) : z4;       // f2(1)
#pragma unroll
    for (int k = 0; k < 2; ++k)
        stB[k] = sVal[k] ? *(const float4*)(f2sp[k] + 2 * HW) : z4;   // f2(2)
    float4 faA = *(const float4*)(f1b);                               // f1(0)
    float4 faB = *(const float4*)(f1b + HW);                          // f1(1)

    float4 qA0 = *(const float4*)(ldr);                               // frags(0)
    float4 qA1 = *(const float4*)(ldr + 4);
    float4 qA2 = *(const float4*)(ldr + 8);
    float4 qB0, qB1, qB2;

#pragma unroll 1
    for (int cc = 0; cc < Cn; cc += 2) {
        // ============ even body: channel cc ============
        {
            // write f2(cc+1) into buffer (frags(cc) already in regs; same-wave
            // ds-pipe ordering makes write-after-read safe, no barrier)
#pragma unroll
            for (int k = 0; k < 2; ++k)
                if (sAct[k]) *(float4*)(&lds[sLds[k]]) = stA[k];

            const float4 a0 = faA;                             // f1(cc)
            const int c3 = (cc + 3 < Cn) ? (cc + 3) : (Cn - 1);
            const int c2 = (cc + 2 < Cn) ? (cc + 2) : (Cn - 1);
#pragma unroll
            for (int k = 0; k < 2; ++k)
                stA[k] = sVal[k] ? *(const float4*)(f2sp[k] + (size_t)c3 * HW) : z4;
            faA = *(const float4*)(f1b + (size_t)c2 * HW);

            const float wv[12] = {qA0.x, qA0.y, qA0.z, qA0.w,
                                  qA1.x, qA1.y, qA1.z, qA1.w,
                                  qA2.x, qA2.y, qA2.z, qA2.w};
#pragma unroll
            for (int dx = 0; dx < 9; ++dx) {
                acc[dx].x += a0.x * wv[dx + 0];
                acc[dx].y += a0.y * wv[dx + 1];
                acc[dx].z += a0.z * wv[dx + 2];
                acc[dx].w += a0.w * wv[dx + 3];
            }
            // frags(cc+1): after this body's write (same-wave lgkm ordering)
            qB0 = *(const float4*)(ldr);
            qB1 = *(const float4*)(ldr + 4);
            qB2 = *(const float4*)(ldr + 8);
        }
        // ============ odd body: channel cc+1 ============
        {
#pragma unroll
            for (int k = 0; k < 2; ++k)
                if (sAct[k]) *(float4*)(&lds[sLds[k]]) = stB[k];   // f2(cc+2)

            const float4 a0 = faB;                             // f1(cc+1)
            const int c4  = (cc + 4 < Cn) ? (cc + 4) : (Cn - 1);
            const int c3b = (cc + 3 < Cn) ? (cc + 3) : (Cn - 1);
#pragma unroll
            for (int k = 0; k < 2; ++k)
                stB[k] = sVal[k] ? *(const float4*)(f2sp[k] + (size_t)c4 * HW) : z4;
            faB = *(const float4*)(f1b + (size_t)c3b * HW);

            const float wv[12] = {qB0.x, qB0.y, qB0.z, qB0.w,
                                  qB1.x, qB1.y, qB1.z, qB1.w,
                                  qB2.x, qB2.y, qB2.z, qB2.w};
#pragma unroll
            for (int dx = 0; dx < 9; ++dx) {
                acc[dx].x += a0.x * wv[dx + 0];
                acc[dx].y += a0.y * wv[dx + 1];
                acc[dx].z += a0.z * wv[dx + 2];
                acc[dx].w += a0.w * wv[dx + 3];
            }
            // frags(cc+2)
            qA0 = *(const float4*)(ldr);
            qA1 = *(const float4*)(ldr + 4);
            qA2 = *(const float4*)(ldr + 8);
        }
    }

    // ---- writeout: 9 float4 per thread, coalesced 16B stores ----
    const float sc = 1.0f / 128.0f;
    float* ob = outg + (size_t)n * 81 * HW + (size_t)hA * Ww + wA;
#pragma unroll
    for (int dx = 0; dx < 9; ++dx) {
        const int k = dy * 9 + dx;
        float4 v = acc[dx];
        v.x *= sc; v.y *= sc; v.z *= sc; v.w *= sc;
        *(float4*)(ob + (size_t)k * HW) = v;
    }
}

extern "C" void kernel_launch(void* const* d_in, const int* in_sizes, int n_in,
                              void* d_out, int out_size, void* d_ws, size_t ws_size,
                              hipStream_t stream) {
    const float* f1 = (const float*)d_in[0];
    const float* f2 = (const float*)d_in[1];
    float* out = (float*)d_out;
    // grid: 672 tiles x 9 dy, swizzled so a tile's 9 waves share an XCD
    costvol_kernel<<<dim3(6048), dim3(64), 0, stream>>>(f1, f2, out);
}